// Round 4
// baseline (253.436 us; speedup 1.0000x reference)
//
#include <hip/hip_runtime.h>
#include <hip/hip_cooperative_groups.h>

namespace cg = cooperative_groups;

#define BN_B 32
#define BN_N 65536
#define THREADS 256

// ---- fused cooperative kernel geometry ----
#define FUSED_BLOCKS 1024
#define CHUNKS_PER_B (FUSED_BLOCKS / BN_B)          // 32
#define PTS_PER_BLOCK (BN_N / CHUNKS_PER_B)         // 2048
#define PTS_PER_THREAD (PTS_PER_BLOCK / THREADS)    // 8

// ---- fallback (3-kernel) geometry ----
#define BLOCKS_PER_B 64
#define STATE_OFFSET (256 * 1024)
#define STATE_BYTES ((size_t)BN_B * BN_N * 16)
#define WS_NEEDED (STATE_OFFSET + STATE_BYTES)

typedef _Float16 half_t;
union HPack { half_t h[2]; unsigned int u; };
struct alignas(16) Half8 { half_t h[8]; };
union StateU { Half8 s; uint4 u; };

__device__ __forceinline__ unsigned int packh(float a, float b) {
    HPack p; p.h[0] = (half_t)a; p.h[1] = (half_t)b; return p.u;
}

// Per-point math. Loads 18 floats.
__device__ __forceinline__ void point_core(
    const float* __restrict__ r, const float* __restrict__ w,
    const float* __restrict__ J_p, const float* __restrict__ J_d,
    size_t p, float lam,
    float jpa[6], float jpb[6], float& c, float& cr0, float& cr1,
    float hpd[6], float& gd, float& ihdd)
{
    float2 wv = *(const float2*)(w + p * 2);
    float2 rv = *(const float2*)(r + p * 2);
    float2 jd = *(const float2*)(J_d + p * 2);
    float4 jp0 = *(const float4*)(J_p + p * 12);
    float4 jp1 = *(const float4*)(J_p + p * 12 + 4);
    float4 jp2 = *(const float4*)(J_p + p * 12 + 8);
    c = wv.x;
    float nl = wv.y;
    jpa[0] = jp0.x; jpa[1] = jp0.y; jpa[2] = jp0.z; jpa[3] = jp0.w; jpa[4] = jp1.x; jpa[5] = jp1.y;
    jpb[0] = jp1.z; jpb[1] = jp1.w; jpb[2] = jp2.x; jpb[3] = jp2.y; jpb[4] = jp2.z; jpb[5] = jp2.w;
    float cjd0 = c * jd.x, cjd1 = c * jd.y;
#pragma unroll
    for (int i = 0; i < 6; ++i) hpd[i] = jpa[i] * cjd0 + jpb[i] * cjd1;
    float hdd = jd.x * cjd0 + jd.y * cjd1;
    cr0 = c * rv.x; cr1 = c * rv.y;
    gd = jd.x * cr0 + jd.y * cr1;
    ihdd = 1.0f / (hdd + lam + nl + 1e-6f);
}

// ======================= fused cooperative kernel =======================
// Per-point state lives in LDS (32 KiB/block), NOT registers -> no spill.
__global__ __launch_bounds__(THREADS, 4) void k_fused(
    const float* __restrict__ r, const float* __restrict__ w,
    const float* __restrict__ J_p, const float* __restrict__ J_d,
    const float* __restrict__ lmbda, float* __restrict__ partials,
    float* __restrict__ out)
{
    __shared__ uint4 st_lds[PTS_PER_BLOCK];   // 32 KiB: fp16 state per point
    __shared__ float red[4][27];
    __shared__ float As[6][7];

    const int b = blockIdx.x / CHUNKS_PER_B;
    const int chunk = blockIdx.x % CHUNKS_PER_B;
    const float lam = lmbda[0];
    const size_t base = (size_t)b * BN_N + (size_t)chunk * PTS_PER_BLOCK + threadIdx.x;

    float acc[27];
#pragma unroll
    for (int i = 0; i < 27; ++i) acc[i] = 0.0f;

#pragma unroll
    for (int kk = 0; kk < PTS_PER_THREAD; ++kk) {
        const size_t p = base + (size_t)kk * THREADS;
        float jpa[6], jpb[6], hpd[6];
        float c, cr0, cr1, gd, ihdd;
        point_core(r, w, J_p, J_d, p, lam, jpa, jpb, c, cr0, cr1, hpd, gd, ihdd);
        float hs[6];
        int t = 0;
#pragma unroll
        for (int i = 0; i < 6; ++i) {
            float ca = c * jpa[i];
            float cb = c * jpb[i];
            hs[i] = ihdd * hpd[i];
#pragma unroll
            for (int j = i; j < 6; ++j, ++t)
                acc[t] += ca * jpa[j] + cb * jpb[j] - hs[i] * hpd[j];
            acc[21 + i] += jpa[i] * cr0 + jpb[i] * cr1 - hs[i] * gd;
        }
        uint4 su;
        su.x = packh(hs[0], hs[1]);
        su.y = packh(hs[2], hs[3]);
        su.z = packh(hs[4], hs[5]);
        su.w = packh(ihdd * gd, 0.0f);
        st_lds[kk * THREADS + threadIdx.x] = su;
    }

    // Wave reduce, then cross-wave via LDS.
#pragma unroll
    for (int i = 0; i < 27; ++i) {
        float v = acc[i];
#pragma unroll
        for (int off = 32; off > 0; off >>= 1) v += __shfl_down(v, off);
        acc[i] = v;
    }
    {
        const int wave = threadIdx.x >> 6;
        const int lane = threadIdx.x & 63;
        if (lane == 0) {
#pragma unroll
            for (int i = 0; i < 27; ++i) red[wave][i] = acc[i];
        }
    }
    __syncthreads();
    if (threadIdx.x < 27) {
        partials[(size_t)blockIdx.x * 27 + threadIdx.x] =
            red[0][threadIdx.x] + red[1][threadIdx.x] +
            red[2][threadIdx.x] + red[3][threadIdx.x];
    }

    cg::this_grid().sync();

    // ---- per-batch 6x6 solve, one solver block per batch (chunk==0) ----
    if (chunk == 0) {
        if (threadIdx.x < 27) {
            float s = 0.0f;
            for (int c2 = 0; c2 < CHUNKS_PER_B; ++c2)
                s += partials[((size_t)b * CHUNKS_PER_B + c2) * 27 + threadIdx.x];
            red[0][threadIdx.x] = s;  // reuse LDS
        }
        __syncthreads();
        if (threadIdx.x == 0) {
            int t = 0;
            for (int i = 0; i < 6; ++i)
                for (int j = i; j < 6; ++j, ++t) { As[i][j] = red[0][t]; As[j][i] = red[0][t]; }
            for (int i = 0; i < 6; ++i) As[i][i] += lam + 0.001f;
            for (int i = 0; i < 6; ++i) As[i][6] = red[0][21 + i];

            // Gaussian elimination with partial pivoting (in LDS: dynamic idx ok)
            for (int col = 0; col < 6; ++col) {
                int piv = col;
                float best = fabsf(As[col][col]);
                for (int rw = col + 1; rw < 6; ++rw) {
                    float v = fabsf(As[rw][col]);
                    if (v > best) { best = v; piv = rw; }
                }
                if (piv != col) {
                    for (int j = 0; j < 7; ++j) {
                        float tmp = As[col][j]; As[col][j] = As[piv][j]; As[piv][j] = tmp;
                    }
                }
                float inv = 1.0f / As[col][col];
                for (int rw = col + 1; rw < 6; ++rw) {
                    float f = As[rw][col] * inv;
                    for (int j = col; j < 7; ++j) As[rw][j] -= f * As[col][j];
                }
            }
            float x[6];
            for (int i = 5; i >= 0; --i) {
                float s = As[i][6];
                for (int j = i + 1; j < 6; ++j) s -= As[i][j] * x[j];
                x[i] = s / As[i][i];
            }
            for (int i = 0; i < 6; ++i) out[b * 6 + i] = x[i];
        }
    }

    cg::this_grid().sync();

    // ---- depth from LDS-resident state ----
    float d[6];
#pragma unroll
    for (int i = 0; i < 6; ++i) d[i] = out[b * 6 + i];
    float* out_depth = out + 192;
#pragma unroll
    for (int kk = 0; kk < PTS_PER_THREAD; ++kk) {
        const size_t p = base + (size_t)kk * THREADS;
        uint4 su = st_lds[kk * THREADS + threadIdx.x];
        HPack p0, p1, p2, p3;
        p0.u = su.x; p1.u = su.y; p2.u = su.z; p3.u = su.w;
        float v = (float)p0.h[0] * d[0] + (float)p0.h[1] * d[1] +
                  (float)p1.h[0] * d[2] + (float)p1.h[1] * d[3] +
                  (float)p2.h[0] * d[4] + (float)p2.h[1] * d[5];
        out_depth[p] = (float)p3.h[0] - v;
    }
}

// ======================= fallback 3-kernel path =======================
template <bool WRITE_STATE>
__global__ __launch_bounds__(THREADS) void k_reduce(
    const float* __restrict__ r, const float* __restrict__ w,
    const float* __restrict__ J_p, const float* __restrict__ J_d,
    const float* __restrict__ lmbda, float* __restrict__ partials,
    uint4* __restrict__ state)
{
    const int b = blockIdx.y;
    const int blk = blockIdx.x;
    const float lam = lmbda[0];

    float acc[27];
#pragma unroll
    for (int i = 0; i < 27; ++i) acc[i] = 0.0f;

    const int n0 = blk * (BN_N / BLOCKS_PER_B);
    const int n1 = n0 + (BN_N / BLOCKS_PER_B);
    const size_t baseP = (size_t)b * BN_N;

    for (int n = n0 + (int)threadIdx.x; n < n1; n += THREADS) {
        size_t p = baseP + n;
        float jpa[6], jpb[6], hpd[6];
        float c, cr0, cr1, gd, ihdd;
        point_core(r, w, J_p, J_d, p, lam, jpa, jpb, c, cr0, cr1, hpd, gd, ihdd);

        StateU su;
        int t = 0;
#pragma unroll
        for (int i = 0; i < 6; ++i) {
            float ca = c * jpa[i];
            float cb = c * jpb[i];
            float hs = ihdd * hpd[i];
#pragma unroll
            for (int j = i; j < 6; ++j, ++t)
                acc[t] += ca * jpa[j] + cb * jpb[j] - hs * hpd[j];
            acc[21 + i] += jpa[i] * cr0 + jpb[i] * cr1 - hs * gd;
            if (WRITE_STATE) su.s.h[i] = (half_t)hs;
        }
        if (WRITE_STATE) {
            su.s.h[6] = (half_t)(ihdd * gd);
            su.s.h[7] = (half_t)0.0f;
            state[p] = su.u;
        }
    }

#pragma unroll
    for (int i = 0; i < 27; ++i) {
        float v = acc[i];
#pragma unroll
        for (int off = 32; off > 0; off >>= 1) v += __shfl_down(v, off);
        acc[i] = v;
    }

    __shared__ float red[4][27];
    const int wave = threadIdx.x >> 6;
    const int lane = threadIdx.x & 63;
    if (lane == 0) {
#pragma unroll
        for (int i = 0; i < 27; ++i) red[wave][i] = acc[i];
    }
    __syncthreads();
    if (threadIdx.x < 27) {
        float s = red[0][threadIdx.x] + red[1][threadIdx.x] +
                  red[2][threadIdx.x] + red[3][threadIdx.x];
        partials[((size_t)b * BLOCKS_PER_B + blk) * 27 + threadIdx.x] = s;
    }
}

__global__ void k_solve(const float* __restrict__ partials,
                        const float* __restrict__ lmbda,
                        float* __restrict__ out)
{
    const int b = blockIdx.x;
    __shared__ float sum27[27];
    __shared__ float As[6][7];
    if (threadIdx.x < 27) {
        float s = 0.0f;
        for (int p = 0; p < BLOCKS_PER_B; ++p)
            s += partials[((size_t)b * BLOCKS_PER_B + p) * 27 + threadIdx.x];
        sum27[threadIdx.x] = s;
    }
    __syncthreads();
    if (threadIdx.x == 0) {
        const float lam = lmbda[0];
        int t = 0;
        for (int i = 0; i < 6; ++i)
            for (int j = i; j < 6; ++j, ++t) { As[i][j] = sum27[t]; As[j][i] = sum27[t]; }
        for (int i = 0; i < 6; ++i) As[i][i] += lam + 0.001f;
        for (int i = 0; i < 6; ++i) As[i][6] = sum27[21 + i];

        for (int col = 0; col < 6; ++col) {
            int piv = col;
            float best = fabsf(As[col][col]);
            for (int rw = col + 1; rw < 6; ++rw) {
                float v = fabsf(As[rw][col]);
                if (v > best) { best = v; piv = rw; }
            }
            if (piv != col) {
                for (int j = 0; j < 7; ++j) {
                    float tmp = As[col][j]; As[col][j] = As[piv][j]; As[piv][j] = tmp;
                }
            }
            float inv = 1.0f / As[col][col];
            for (int rw = col + 1; rw < 6; ++rw) {
                float f = As[rw][col] * inv;
                for (int j = col; j < 7; ++j) As[rw][j] -= f * As[col][j];
            }
        }
        float x[6];
        for (int i = 5; i >= 0; --i) {
            float s = As[i][6];
            for (int j = i + 1; j < 6; ++j) s -= As[i][j] * x[j];
            x[i] = s / As[i][i];
        }
        for (int i = 0; i < 6; ++i) out[b * 6 + i] = x[i];
    }
}

__global__ __launch_bounds__(THREADS) void k_depth2(
    const uint4* __restrict__ state, const float* __restrict__ dp,
    float* __restrict__ out_depth)
{
    const int b = blockIdx.y;
    const int blk = blockIdx.x;
    float d[6];
#pragma unroll
    for (int i = 0; i < 6; ++i) d[i] = dp[b * 6 + i];

    const int n0 = blk * (BN_N / BLOCKS_PER_B);
    const int n1 = n0 + (BN_N / BLOCKS_PER_B);
    const size_t baseP = (size_t)b * BN_N;

    for (int n = n0 + (int)threadIdx.x; n < n1; n += THREADS) {
        size_t p = baseP + n;
        StateU su;
        su.u = state[p];
        float v = 0.0f;
#pragma unroll
        for (int i = 0; i < 6; ++i) v += (float)su.s.h[i] * d[i];
        out_depth[p] = (float)su.s.h[6] - v;
    }
}

extern "C" void kernel_launch(void* const* d_in, const int* in_sizes, int n_in,
                              void* d_out, int out_size, void* d_ws, size_t ws_size,
                              hipStream_t stream) {
    const float* r     = (const float*)d_in[0];
    const float* w     = (const float*)d_in[1];
    const float* J_p   = (const float*)d_in[2];
    const float* J_d   = (const float*)d_in[3];
    const float* lmbda = (const float*)d_in[4];
    float* out = (float*)d_out;
    float* partials = (float*)d_ws;

    void* args[] = {(void*)&r, (void*)&w, (void*)&J_p, (void*)&J_d,
                    (void*)&lmbda, (void*)&partials, (void*)&out};
    hipError_t err = hipLaunchCooperativeKernel(
        (const void*)k_fused, dim3(FUSED_BLOCKS), dim3(THREADS), args, 0, stream);

    if (err != hipSuccess) {
        // Fallback: proven 3-kernel path with fp16 state stash.
        uint4* state = (uint4*)((char*)d_ws + STATE_OFFSET);
        dim3 grid(BLOCKS_PER_B, BN_B);
        if (ws_size >= WS_NEEDED) {
            k_reduce<true><<<grid, THREADS, 0, stream>>>(r, w, J_p, J_d, lmbda, partials, state);
            k_solve<<<dim3(BN_B), 32, 0, stream>>>(partials, lmbda, out);
            k_depth2<<<grid, THREADS, 0, stream>>>(state, out, out + 192);
        } else {
            k_reduce<false><<<grid, THREADS, 0, stream>>>(r, w, J_p, J_d, lmbda, partials, nullptr);
            k_solve<<<dim3(BN_B), 32, 0, stream>>>(partials, lmbda, out);
            k_depth2<<<grid, THREADS, 0, stream>>>(state, out, out + 192);
        }
    }
}

// Round 5
// 163.958 us; speedup vs baseline: 1.5457x; 1.5457x over previous
//
#include <hip/hip_runtime.h>

#define BN_B 32
#define BN_N 65536
#define THREADS 256

// ---- fused cooperative kernel geometry ----
#define FUSED_BLOCKS 2048
#define CHUNKS_PER_B (FUSED_BLOCKS / BN_B)          // 64
#define PTS_PER_BLOCK (BN_N / CHUNKS_PER_B)         // 1024
#define PTS_PER_THREAD (PTS_PER_BLOCK / THREADS)    // 4

// ---- workspace layout ----
// [0, FUSED_BLOCKS*27*4)   partials (221184 B)
// [BAR_OFF + b*128)        counters (int, 1 per batch, 128B stride)
// [BAR_OFF + 4096 + b*128) flags    (int, 1 per batch)
// [BAR_OFF + 8192 + b*128) dp_pub   (6 floats per batch)
#define BAR_OFF (256 * 1024)
#define FUSED_WS_NEEDED (BAR_OFF + 12288)

// ---- fallback (3-kernel) geometry ----
#define BLOCKS_PER_B 64
#define STATE_OFFSET (512 * 1024)
#define STATE_BYTES ((size_t)BN_B * BN_N * 16)
#define WS_NEEDED (STATE_OFFSET + STATE_BYTES)

typedef _Float16 half_t;
union HPack { half_t h[2]; unsigned int u; };
struct alignas(16) Half8 { half_t h[8]; };
union StateU { Half8 s; uint4 u; };

__device__ __forceinline__ unsigned int packh(float a, float b) {
    HPack p; p.h[0] = (half_t)a; p.h[1] = (half_t)b; return p.u;
}

// Per-point math. Loads 18 floats.
__device__ __forceinline__ void point_core(
    const float* __restrict__ r, const float* __restrict__ w,
    const float* __restrict__ J_p, const float* __restrict__ J_d,
    size_t p, float lam,
    float jpa[6], float jpb[6], float& c, float& cr0, float& cr1,
    float hpd[6], float& gd, float& ihdd)
{
    float2 wv = *(const float2*)(w + p * 2);
    float2 rv = *(const float2*)(r + p * 2);
    float2 jd = *(const float2*)(J_d + p * 2);
    float4 jp0 = *(const float4*)(J_p + p * 12);
    float4 jp1 = *(const float4*)(J_p + p * 12 + 4);
    float4 jp2 = *(const float4*)(J_p + p * 12 + 8);
    c = wv.x;
    float nl = wv.y;
    jpa[0] = jp0.x; jpa[1] = jp0.y; jpa[2] = jp0.z; jpa[3] = jp0.w; jpa[4] = jp1.x; jpa[5] = jp1.y;
    jpb[0] = jp1.z; jpb[1] = jp1.w; jpb[2] = jp2.x; jpb[3] = jp2.y; jpb[4] = jp2.z; jpb[5] = jp2.w;
    float cjd0 = c * jd.x, cjd1 = c * jd.y;
#pragma unroll
    for (int i = 0; i < 6; ++i) hpd[i] = jpa[i] * cjd0 + jpb[i] * cjd1;
    float hdd = jd.x * cjd0 + jd.y * cjd1;
    cr0 = c * rv.x; cr1 = c * rv.y;
    gd = jd.x * cr0 + jd.y * cr1;
    ihdd = 1.0f / (hdd + lam + nl + 1e-6f);
}

// Shared 6x6 solve (LDS matrix, 1 thread). As is [6][7] augmented.
__device__ __forceinline__ void solve6(volatile float As[6][7], float x[6]) {
    for (int col = 0; col < 6; ++col) {
        int piv = col;
        float best = fabsf(As[col][col]);
        for (int rw = col + 1; rw < 6; ++rw) {
            float v = fabsf(As[rw][col]);
            if (v > best) { best = v; piv = rw; }
        }
        if (piv != col) {
            for (int j = 0; j < 7; ++j) {
                float tmp = As[col][j]; As[col][j] = As[piv][j]; As[piv][j] = tmp;
            }
        }
        float inv = 1.0f / As[col][col];
        for (int rw = col + 1; rw < 6; ++rw) {
            float f = As[rw][col] * inv;
            for (int j = col; j < 7; ++j) As[rw][j] -= f * As[col][j];
        }
    }
    for (int i = 5; i >= 0; --i) {
        float s = As[i][6];
        for (int j = i + 1; j < 6; ++j) s -= As[i][j] * x[j];
        x[i] = s / As[i][i];
    }
}

// ======================= fused cooperative kernel =======================
// Per-batch atomic barrier instead of cg grid.sync (which costs ~90us each).
__global__ __launch_bounds__(THREADS, 8) void k_fused2(
    const float* __restrict__ r, const float* __restrict__ w,
    const float* __restrict__ J_p, const float* __restrict__ J_d,
    const float* __restrict__ lmbda, char* __restrict__ ws,
    float* __restrict__ out)
{
    __shared__ uint4 st_lds[PTS_PER_BLOCK];   // 16 KiB fp16 state
    __shared__ float red[4][27];
    __shared__ float As[6][7];
    __shared__ float dp_s[6];

    float* partials = (float*)ws;
    int*   cnt  = (int*)(ws + BAR_OFF);          // stride 32 ints
    int*   flag = (int*)(ws + BAR_OFF + 4096);   // stride 32 ints
    float* dpp  = (float*)(ws + BAR_OFF + 8192); // stride 32 floats

    const int b = blockIdx.x / CHUNKS_PER_B;
    const int chunk = blockIdx.x % CHUNKS_PER_B;
    const float lam = lmbda[0];
    const size_t base = (size_t)b * BN_N + (size_t)chunk * PTS_PER_BLOCK + threadIdx.x;

    float acc[27];
#pragma unroll
    for (int i = 0; i < 27; ++i) acc[i] = 0.0f;

#pragma unroll
    for (int kk = 0; kk < PTS_PER_THREAD; ++kk) {
        const size_t p = base + (size_t)kk * THREADS;
        float jpa[6], jpb[6], hpd[6];
        float c, cr0, cr1, gd, ihdd;
        point_core(r, w, J_p, J_d, p, lam, jpa, jpb, c, cr0, cr1, hpd, gd, ihdd);
        float hs[6];
        int t = 0;
#pragma unroll
        for (int i = 0; i < 6; ++i) {
            float ca = c * jpa[i];
            float cb = c * jpb[i];
            hs[i] = ihdd * hpd[i];
#pragma unroll
            for (int j = i; j < 6; ++j, ++t)
                acc[t] += ca * jpa[j] + cb * jpb[j] - hs[i] * hpd[j];
            acc[21 + i] += jpa[i] * cr0 + jpb[i] * cr1 - hs[i] * gd;
        }
        uint4 su;
        su.x = packh(hs[0], hs[1]);
        su.y = packh(hs[2], hs[3]);
        su.z = packh(hs[4], hs[5]);
        su.w = packh(ihdd * gd, 0.0f);
        st_lds[kk * THREADS + threadIdx.x] = su;
    }

    // Wave reduce, then cross-wave via LDS.
#pragma unroll
    for (int i = 0; i < 27; ++i) {
        float v = acc[i];
#pragma unroll
        for (int off = 32; off > 0; off >>= 1) v += __shfl_down(v, off);
        acc[i] = v;
    }
    {
        const int wave = threadIdx.x >> 6;
        const int lane = threadIdx.x & 63;
        if (lane == 0) {
#pragma unroll
            for (int i = 0; i < 27; ++i) red[wave][i] = acc[i];
        }
    }
    __syncthreads();
    // Wave 0 (threads 0..26) writes this block's partials, then thread 0
    // publishes arrival with a RELEASE add (same wave -> ordered).
    if (threadIdx.x < 27) {
        partials[(size_t)blockIdx.x * 27 + threadIdx.x] =
            red[0][threadIdx.x] + red[1][threadIdx.x] +
            red[2][threadIdx.x] + red[3][threadIdx.x];
    }
    if (threadIdx.x == 0) {
        __hip_atomic_fetch_add(&cnt[b * 32], 1, __ATOMIC_RELEASE,
                               __HIP_MEMORY_SCOPE_AGENT);
    }

    if (chunk == 0) {
        // Solver block: wait for all 64 chunks of this batch.
        if (threadIdx.x == 0) {
            while (__hip_atomic_load(&cnt[b * 32], __ATOMIC_RELAXED,
                                     __HIP_MEMORY_SCOPE_AGENT) < CHUNKS_PER_B)
                __builtin_amdgcn_s_sleep(1);
        }
        __syncthreads();
        __builtin_amdgcn_fence(__ATOMIC_ACQUIRE, "agent");
        if (threadIdx.x < 27) {
            float s = 0.0f;
            for (int c2 = 0; c2 < CHUNKS_PER_B; ++c2)
                s += partials[((size_t)b * CHUNKS_PER_B + c2) * 27 + threadIdx.x];
            red[0][threadIdx.x] = s;
        }
        __syncthreads();
        if (threadIdx.x == 0) {
            int t = 0;
            for (int i = 0; i < 6; ++i)
                for (int j = i; j < 6; ++j, ++t) { As[i][j] = red[0][t]; As[j][i] = red[0][t]; }
            for (int i = 0; i < 6; ++i) As[i][i] += lam + 0.001f;
            for (int i = 0; i < 6; ++i) As[i][6] = red[0][21 + i];
            float x[6];
            solve6(As, x);
            for (int i = 0; i < 6; ++i) {
                out[b * 6 + i] = x[i];
                dp_s[i] = x[i];
                __hip_atomic_store(&dpp[b * 32 + i], x[i], __ATOMIC_RELAXED,
                                   __HIP_MEMORY_SCOPE_AGENT);
            }
            __hip_atomic_store(&flag[b * 32], 1, __ATOMIC_RELEASE,
                               __HIP_MEMORY_SCOPE_AGENT);
        }
        __syncthreads();
    } else {
        if (threadIdx.x == 0) {
            while (__hip_atomic_load(&flag[b * 32], __ATOMIC_RELAXED,
                                     __HIP_MEMORY_SCOPE_AGENT) == 0)
                __builtin_amdgcn_s_sleep(1);
#pragma unroll
            for (int i = 0; i < 6; ++i)
                dp_s[i] = __hip_atomic_load(&dpp[b * 32 + i], __ATOMIC_RELAXED,
                                            __HIP_MEMORY_SCOPE_AGENT);
        }
        __syncthreads();
    }

    // ---- depth from LDS-resident state ----
    float d[6];
#pragma unroll
    for (int i = 0; i < 6; ++i) d[i] = dp_s[i];
    float* out_depth = out + 192;
#pragma unroll
    for (int kk = 0; kk < PTS_PER_THREAD; ++kk) {
        const size_t p = base + (size_t)kk * THREADS;
        uint4 su = st_lds[kk * THREADS + threadIdx.x];
        HPack p0, p1, p2, p3;
        p0.u = su.x; p1.u = su.y; p2.u = su.z; p3.u = su.w;
        float v = (float)p0.h[0] * d[0] + (float)p0.h[1] * d[1] +
                  (float)p1.h[0] * d[2] + (float)p1.h[1] * d[3] +
                  (float)p2.h[0] * d[4] + (float)p2.h[1] * d[5];
        out_depth[p] = (float)p3.h[0] - v;
    }
}

// ======================= fallback 3-kernel path =======================
template <bool WRITE_STATE>
__global__ __launch_bounds__(THREADS) void k_reduce(
    const float* __restrict__ r, const float* __restrict__ w,
    const float* __restrict__ J_p, const float* __restrict__ J_d,
    const float* __restrict__ lmbda, float* __restrict__ partials,
    uint4* __restrict__ state)
{
    const int b = blockIdx.y;
    const int blk = blockIdx.x;
    const float lam = lmbda[0];

    float acc[27];
#pragma unroll
    for (int i = 0; i < 27; ++i) acc[i] = 0.0f;

    const int n0 = blk * (BN_N / BLOCKS_PER_B);
    const int n1 = n0 + (BN_N / BLOCKS_PER_B);
    const size_t baseP = (size_t)b * BN_N;

    for (int n = n0 + (int)threadIdx.x; n < n1; n += THREADS) {
        size_t p = baseP + n;
        float jpa[6], jpb[6], hpd[6];
        float c, cr0, cr1, gd, ihdd;
        point_core(r, w, J_p, J_d, p, lam, jpa, jpb, c, cr0, cr1, hpd, gd, ihdd);

        StateU su;
        int t = 0;
#pragma unroll
        for (int i = 0; i < 6; ++i) {
            float ca = c * jpa[i];
            float cb = c * jpb[i];
            float hs = ihdd * hpd[i];
#pragma unroll
            for (int j = i; j < 6; ++j, ++t)
                acc[t] += ca * jpa[j] + cb * jpb[j] - hs * hpd[j];
            acc[21 + i] += jpa[i] * cr0 + jpb[i] * cr1 - hs * gd;
            if (WRITE_STATE) su.s.h[i] = (half_t)hs;
        }
        if (WRITE_STATE) {
            su.s.h[6] = (half_t)(ihdd * gd);
            su.s.h[7] = (half_t)0.0f;
            state[p] = su.u;
        }
    }

#pragma unroll
    for (int i = 0; i < 27; ++i) {
        float v = acc[i];
#pragma unroll
        for (int off = 32; off > 0; off >>= 1) v += __shfl_down(v, off);
        acc[i] = v;
    }

    __shared__ float red[4][27];
    const int wave = threadIdx.x >> 6;
    const int lane = threadIdx.x & 63;
    if (lane == 0) {
#pragma unroll
        for (int i = 0; i < 27; ++i) red[wave][i] = acc[i];
    }
    __syncthreads();
    if (threadIdx.x < 27) {
        float s = red[0][threadIdx.x] + red[1][threadIdx.x] +
                  red[2][threadIdx.x] + red[3][threadIdx.x];
        partials[((size_t)b * BLOCKS_PER_B + blk) * 27 + threadIdx.x] = s;
    }
}

__global__ void k_solve(const float* __restrict__ partials,
                        const float* __restrict__ lmbda,
                        float* __restrict__ out)
{
    const int b = blockIdx.x;
    __shared__ float sum27[27];
    __shared__ float As[6][7];
    if (threadIdx.x < 27) {
        float s = 0.0f;
        for (int p = 0; p < BLOCKS_PER_B; ++p)
            s += partials[((size_t)b * BLOCKS_PER_B + p) * 27 + threadIdx.x];
        sum27[threadIdx.x] = s;
    }
    __syncthreads();
    if (threadIdx.x == 0) {
        const float lam = lmbda[0];
        int t = 0;
        for (int i = 0; i < 6; ++i)
            for (int j = i; j < 6; ++j, ++t) { As[i][j] = sum27[t]; As[j][i] = sum27[t]; }
        for (int i = 0; i < 6; ++i) As[i][i] += lam + 0.001f;
        for (int i = 0; i < 6; ++i) As[i][6] = sum27[21 + i];
        float x[6];
        solve6(As, x);
        for (int i = 0; i < 6; ++i) out[b * 6 + i] = x[i];
    }
}

__global__ __launch_bounds__(THREADS) void k_depth2(
    const uint4* __restrict__ state, const float* __restrict__ dp,
    float* __restrict__ out_depth)
{
    const int b = blockIdx.y;
    const int blk = blockIdx.x;
    float d[6];
#pragma unroll
    for (int i = 0; i < 6; ++i) d[i] = dp[b * 6 + i];

    const int n0 = blk * (BN_N / BLOCKS_PER_B);
    const int n1 = n0 + (BN_N / BLOCKS_PER_B);
    const size_t baseP = (size_t)b * BN_N;

    for (int n = n0 + (int)threadIdx.x; n < n1; n += THREADS) {
        size_t p = baseP + n;
        StateU su;
        su.u = state[p];
        float v = 0.0f;
#pragma unroll
        for (int i = 0; i < 6; ++i) v += (float)su.s.h[i] * d[i];
        out_depth[p] = (float)su.s.h[6] - v;
    }
}

extern "C" void kernel_launch(void* const* d_in, const int* in_sizes, int n_in,
                              void* d_out, int out_size, void* d_ws, size_t ws_size,
                              hipStream_t stream) {
    const float* r     = (const float*)d_in[0];
    const float* w     = (const float*)d_in[1];
    const float* J_p   = (const float*)d_in[2];
    const float* J_d   = (const float*)d_in[3];
    const float* lmbda = (const float*)d_in[4];
    float* out = (float*)d_out;
    char* ws = (char*)d_ws;

    hipError_t err = hipErrorUnknown;
    if (ws_size >= FUSED_WS_NEEDED) {
        // Zero barrier state (counters + flags) every call: ws is not
        // re-poisoned between graph replays, so we must reset it ourselves.
        hipMemsetAsync(ws + BAR_OFF, 0, 8192, stream);
        void* args[] = {(void*)&r, (void*)&w, (void*)&J_p, (void*)&J_d,
                        (void*)&lmbda, (void*)&ws, (void*)&out};
        err = hipLaunchCooperativeKernel(
            (const void*)k_fused2, dim3(FUSED_BLOCKS), dim3(THREADS), args, 0, stream);
    }

    if (err != hipSuccess) {
        // Fallback: proven 3-kernel path with fp16 state stash.
        float* partials = (float*)d_ws;
        uint4* state = (uint4*)(ws + STATE_OFFSET);
        dim3 grid(BLOCKS_PER_B, BN_B);
        if (ws_size >= WS_NEEDED) {
            k_reduce<true><<<grid, THREADS, 0, stream>>>(r, w, J_p, J_d, lmbda, partials, state);
            k_solve<<<dim3(BN_B), 32, 0, stream>>>(partials, lmbda, out);
            k_depth2<<<grid, THREADS, 0, stream>>>(state, out, out + 192);
        } else {
            k_reduce<false><<<grid, THREADS, 0, stream>>>(r, w, J_p, J_d, lmbda, partials, nullptr);
            k_solve<<<dim3(BN_B), 32, 0, stream>>>(partials, lmbda, out);
            k_depth2<<<grid, THREADS, 0, stream>>>(state, out, out + 192);
        }
    }
}

// Round 6
// 102.911 us; speedup vs baseline: 2.4627x; 1.5932x over previous
//
#include <hip/hip_runtime.h>

#define BN_B 32
#define BN_N 65536
#define THREADS 256

// ---- fused cooperative kernel geometry ----
// 1024 blocks @ 4 blocks/CU (co-resident on 256 CUs). VGPR cap 128 -> no spill.
#define FUSED_BLOCKS 1024
#define CHUNKS_PER_B (FUSED_BLOCKS / BN_B)          // 32
#define PTS_PER_BLOCK (BN_N / CHUNKS_PER_B)         // 2048
#define PTS_PER_THREAD (PTS_PER_BLOCK / THREADS)    // 8

// ---- workspace layout ----
// [0, FUSED_BLOCKS*27*4)   partials
// [BAR_OFF + b*128)        counters (int, per batch, 128B stride)
// [BAR_OFF + 4096 + b*128) flags
// [BAR_OFF + 8192 + b*128) dp_pub (6 floats per batch)
#define BAR_OFF (256 * 1024)
#define FUSED_WS_NEEDED (BAR_OFF + 12288)

// ---- fallback (3-kernel) geometry ----
#define BLOCKS_PER_B 64
#define STATE_OFFSET (512 * 1024)
#define STATE_BYTES ((size_t)BN_B * BN_N * 16)
#define WS_NEEDED (STATE_OFFSET + STATE_BYTES)

typedef _Float16 half_t;
union HPack { half_t h[2]; unsigned int u; };
struct alignas(16) Half8 { half_t h[8]; };
union StateU { Half8 s; uint4 u; };

__device__ __forceinline__ unsigned int packh(float a, float b) {
    HPack p; p.h[0] = (half_t)a; p.h[1] = (half_t)b; return p.u;
}

// Per-point math. Loads 18 floats.
__device__ __forceinline__ void point_core(
    const float* __restrict__ r, const float* __restrict__ w,
    const float* __restrict__ J_p, const float* __restrict__ J_d,
    size_t p, float lam,
    float jpa[6], float jpb[6], float& c, float& cr0, float& cr1,
    float hpd[6], float& gd, float& ihdd)
{
    float2 wv = *(const float2*)(w + p * 2);
    float2 rv = *(const float2*)(r + p * 2);
    float2 jd = *(const float2*)(J_d + p * 2);
    float4 jp0 = *(const float4*)(J_p + p * 12);
    float4 jp1 = *(const float4*)(J_p + p * 12 + 4);
    float4 jp2 = *(const float4*)(J_p + p * 12 + 8);
    c = wv.x;
    float nl = wv.y;
    jpa[0] = jp0.x; jpa[1] = jp0.y; jpa[2] = jp0.z; jpa[3] = jp0.w; jpa[4] = jp1.x; jpa[5] = jp1.y;
    jpb[0] = jp1.z; jpb[1] = jp1.w; jpb[2] = jp2.x; jpb[3] = jp2.y; jpb[4] = jp2.z; jpb[5] = jp2.w;
    float cjd0 = c * jd.x, cjd1 = c * jd.y;
#pragma unroll
    for (int i = 0; i < 6; ++i) hpd[i] = jpa[i] * cjd0 + jpb[i] * cjd1;
    float hdd = jd.x * cjd0 + jd.y * cjd1;
    cr0 = c * rv.x; cr1 = c * rv.y;
    gd = jd.x * cr0 + jd.y * cr1;
    ihdd = 1.0f / (hdd + lam + nl + 1e-6f);
}

// 6x6 solve (LDS matrix, 1 thread). As is [6][7] augmented.
__device__ __forceinline__ void solve6(volatile float As[6][7], float x[6]) {
    for (int col = 0; col < 6; ++col) {
        int piv = col;
        float best = fabsf(As[col][col]);
        for (int rw = col + 1; rw < 6; ++rw) {
            float v = fabsf(As[rw][col]);
            if (v > best) { best = v; piv = rw; }
        }
        if (piv != col) {
            for (int j = 0; j < 7; ++j) {
                float tmp = As[col][j]; As[col][j] = As[piv][j]; As[piv][j] = tmp;
            }
        }
        float inv = 1.0f / As[col][col];
        for (int rw = col + 1; rw < 6; ++rw) {
            float f = As[rw][col] * inv;
            for (int j = col; j < 7; ++j) As[rw][j] -= f * As[col][j];
        }
    }
    for (int i = 5; i >= 0; --i) {
        float s = As[i][6];
        for (int j = i + 1; j < 6; ++j) s -= As[i][j] * x[j];
        x[i] = s / As[i][i];
    }
}

// ======================= fused cooperative kernel =======================
// Per-batch atomic barrier (cheap) + LDS-resident per-point state (no spill).
__global__ __launch_bounds__(THREADS, 4) void k_fused3(
    const float* __restrict__ r, const float* __restrict__ w,
    const float* __restrict__ J_p, const float* __restrict__ J_d,
    const float* __restrict__ lmbda, char* __restrict__ ws,
    float* __restrict__ out)
{
    __shared__ uint4 st_lds[PTS_PER_BLOCK];   // 32 KiB fp16 state
    __shared__ float red[4][27];
    __shared__ float As[6][7];
    __shared__ float dp_s[6];

    float* partials = (float*)ws;
    int*   cnt  = (int*)(ws + BAR_OFF);          // stride 32 ints
    int*   flag = (int*)(ws + BAR_OFF + 4096);   // stride 32 ints
    float* dpp  = (float*)(ws + BAR_OFF + 8192); // stride 32 floats

    const int b = blockIdx.x / CHUNKS_PER_B;
    const int chunk = blockIdx.x % CHUNKS_PER_B;
    const float lam = lmbda[0];
    const size_t base = (size_t)b * BN_N + (size_t)chunk * PTS_PER_BLOCK + threadIdx.x;

    float acc[27];
#pragma unroll
    for (int i = 0; i < 27; ++i) acc[i] = 0.0f;

#pragma unroll
    for (int kk = 0; kk < PTS_PER_THREAD; ++kk) {
        const size_t p = base + (size_t)kk * THREADS;
        float jpa[6], jpb[6], hpd[6];
        float c, cr0, cr1, gd, ihdd;
        point_core(r, w, J_p, J_d, p, lam, jpa, jpb, c, cr0, cr1, hpd, gd, ihdd);
        float hs[6];
        int t = 0;
#pragma unroll
        for (int i = 0; i < 6; ++i) {
            float ca = c * jpa[i];
            float cb = c * jpb[i];
            hs[i] = ihdd * hpd[i];
#pragma unroll
            for (int j = i; j < 6; ++j, ++t)
                acc[t] += ca * jpa[j] + cb * jpb[j] - hs[i] * hpd[j];
            acc[21 + i] += jpa[i] * cr0 + jpb[i] * cr1 - hs[i] * gd;
        }
        uint4 su;
        su.x = packh(hs[0], hs[1]);
        su.y = packh(hs[2], hs[3]);
        su.z = packh(hs[4], hs[5]);
        su.w = packh(ihdd * gd, 0.0f);
        st_lds[kk * THREADS + threadIdx.x] = su;
    }

    // Wave reduce, then cross-wave via LDS.
#pragma unroll
    for (int i = 0; i < 27; ++i) {
        float v = acc[i];
#pragma unroll
        for (int off = 32; off > 0; off >>= 1) v += __shfl_down(v, off);
        acc[i] = v;
    }
    {
        const int wave = threadIdx.x >> 6;
        const int lane = threadIdx.x & 63;
        if (lane == 0) {
#pragma unroll
            for (int i = 0; i < 27; ++i) red[wave][i] = acc[i];
        }
    }
    __syncthreads();
    // Threads 0..26 (wave 0) write this block's partials; thread 0 then
    // publishes arrival with a RELEASE add (same wave -> stores drained first).
    if (threadIdx.x < 27) {
        partials[(size_t)blockIdx.x * 27 + threadIdx.x] =
            red[0][threadIdx.x] + red[1][threadIdx.x] +
            red[2][threadIdx.x] + red[3][threadIdx.x];
    }
    if (threadIdx.x == 0) {
        __hip_atomic_fetch_add(&cnt[b * 32], 1, __ATOMIC_RELEASE,
                               __HIP_MEMORY_SCOPE_AGENT);
    }

    if (chunk == 0) {
        // Solver block: wait for all chunks of this batch.
        if (threadIdx.x == 0) {
            while (__hip_atomic_load(&cnt[b * 32], __ATOMIC_RELAXED,
                                     __HIP_MEMORY_SCOPE_AGENT) < CHUNKS_PER_B)
                __builtin_amdgcn_s_sleep(1);
        }
        __syncthreads();
        __builtin_amdgcn_fence(__ATOMIC_ACQUIRE, "agent");
        if (threadIdx.x < 27) {
            float s = 0.0f;
            for (int c2 = 0; c2 < CHUNKS_PER_B; ++c2)
                s += partials[((size_t)b * CHUNKS_PER_B + c2) * 27 + threadIdx.x];
            red[0][threadIdx.x] = s;
        }
        __syncthreads();
        if (threadIdx.x == 0) {
            int t = 0;
            for (int i = 0; i < 6; ++i)
                for (int j = i; j < 6; ++j, ++t) { As[i][j] = red[0][t]; As[j][i] = red[0][t]; }
            for (int i = 0; i < 6; ++i) As[i][i] += lam + 0.001f;
            for (int i = 0; i < 6; ++i) As[i][6] = red[0][21 + i];
            float x[6];
            solve6(As, x);
            for (int i = 0; i < 6; ++i) {
                out[b * 6 + i] = x[i];
                dp_s[i] = x[i];
                __hip_atomic_store(&dpp[b * 32 + i], x[i], __ATOMIC_RELAXED,
                                   __HIP_MEMORY_SCOPE_AGENT);
            }
            __hip_atomic_store(&flag[b * 32], 1, __ATOMIC_RELEASE,
                               __HIP_MEMORY_SCOPE_AGENT);
        }
        __syncthreads();
    } else {
        if (threadIdx.x == 0) {
            while (__hip_atomic_load(&flag[b * 32], __ATOMIC_RELAXED,
                                     __HIP_MEMORY_SCOPE_AGENT) == 0)
                __builtin_amdgcn_s_sleep(1);
            __builtin_amdgcn_fence(__ATOMIC_ACQUIRE, "agent");
#pragma unroll
            for (int i = 0; i < 6; ++i)
                dp_s[i] = __hip_atomic_load(&dpp[b * 32 + i], __ATOMIC_RELAXED,
                                            __HIP_MEMORY_SCOPE_AGENT);
        }
        __syncthreads();
    }

    // ---- depth from LDS-resident state ----
    float d[6];
#pragma unroll
    for (int i = 0; i < 6; ++i) d[i] = dp_s[i];
    float* out_depth = out + 192;
#pragma unroll
    for (int kk = 0; kk < PTS_PER_THREAD; ++kk) {
        const size_t p = base + (size_t)kk * THREADS;
        uint4 su = st_lds[kk * THREADS + threadIdx.x];
        HPack p0, p1, p2, p3;
        p0.u = su.x; p1.u = su.y; p2.u = su.z; p3.u = su.w;
        float v = (float)p0.h[0] * d[0] + (float)p0.h[1] * d[1] +
                  (float)p1.h[0] * d[2] + (float)p1.h[1] * d[3] +
                  (float)p2.h[0] * d[4] + (float)p2.h[1] * d[5];
        out_depth[p] = (float)p3.h[0] - v;
    }
}

// ======================= fallback 3-kernel path =======================
template <bool WRITE_STATE>
__global__ __launch_bounds__(THREADS) void k_reduce(
    const float* __restrict__ r, const float* __restrict__ w,
    const float* __restrict__ J_p, const float* __restrict__ J_d,
    const float* __restrict__ lmbda, float* __restrict__ partials,
    uint4* __restrict__ state)
{
    const int b = blockIdx.y;
    const int blk = blockIdx.x;
    const float lam = lmbda[0];

    float acc[27];
#pragma unroll
    for (int i = 0; i < 27; ++i) acc[i] = 0.0f;

    const int n0 = blk * (BN_N / BLOCKS_PER_B);
    const int n1 = n0 + (BN_N / BLOCKS_PER_B);
    const size_t baseP = (size_t)b * BN_N;

    for (int n = n0 + (int)threadIdx.x; n < n1; n += THREADS) {
        size_t p = baseP + n;
        float jpa[6], jpb[6], hpd[6];
        float c, cr0, cr1, gd, ihdd;
        point_core(r, w, J_p, J_d, p, lam, jpa, jpb, c, cr0, cr1, hpd, gd, ihdd);

        StateU su;
        int t = 0;
#pragma unroll
        for (int i = 0; i < 6; ++i) {
            float ca = c * jpa[i];
            float cb = c * jpb[i];
            float hs = ihdd * hpd[i];
#pragma unroll
            for (int j = i; j < 6; ++j, ++t)
                acc[t] += ca * jpa[j] + cb * jpb[j] - hs * hpd[j];
            acc[21 + i] += jpa[i] * cr0 + jpb[i] * cr1 - hs * gd;
            if (WRITE_STATE) su.s.h[i] = (half_t)hs;
        }
        if (WRITE_STATE) {
            su.s.h[6] = (half_t)(ihdd * gd);
            su.s.h[7] = (half_t)0.0f;
            state[p] = su.u;
        }
    }

#pragma unroll
    for (int i = 0; i < 27; ++i) {
        float v = acc[i];
#pragma unroll
        for (int off = 32; off > 0; off >>= 1) v += __shfl_down(v, off);
        acc[i] = v;
    }

    __shared__ float red[4][27];
    const int wave = threadIdx.x >> 6;
    const int lane = threadIdx.x & 63;
    if (lane == 0) {
#pragma unroll
        for (int i = 0; i < 27; ++i) red[wave][i] = acc[i];
    }
    __syncthreads();
    if (threadIdx.x < 27) {
        float s = red[0][threadIdx.x] + red[1][threadIdx.x] +
                  red[2][threadIdx.x] + red[3][threadIdx.x];
        partials[((size_t)b * BLOCKS_PER_B + blk) * 27 + threadIdx.x] = s;
    }
}

__global__ void k_solve(const float* __restrict__ partials,
                        const float* __restrict__ lmbda,
                        float* __restrict__ out)
{
    const int b = blockIdx.x;
    __shared__ float sum27[27];
    __shared__ float As[6][7];
    if (threadIdx.x < 27) {
        float s = 0.0f;
        for (int p = 0; p < BLOCKS_PER_B; ++p)
            s += partials[((size_t)b * BLOCKS_PER_B + p) * 27 + threadIdx.x];
        sum27[threadIdx.x] = s;
    }
    __syncthreads();
    if (threadIdx.x == 0) {
        const float lam = lmbda[0];
        int t = 0;
        for (int i = 0; i < 6; ++i)
            for (int j = i; j < 6; ++j, ++t) { As[i][j] = sum27[t]; As[j][i] = sum27[t]; }
        for (int i = 0; i < 6; ++i) As[i][i] += lam + 0.001f;
        for (int i = 0; i < 6; ++i) As[i][6] = sum27[21 + i];
        float x[6];
        solve6(As, x);
        for (int i = 0; i < 6; ++i) out[b * 6 + i] = x[i];
    }
}

__global__ __launch_bounds__(THREADS) void k_depth2(
    const uint4* __restrict__ state, const float* __restrict__ dp,
    float* __restrict__ out_depth)
{
    const int b = blockIdx.y;
    const int blk = blockIdx.x;
    float d[6];
#pragma unroll
    for (int i = 0; i < 6; ++i) d[i] = dp[b * 6 + i];

    const int n0 = blk * (BN_N / BLOCKS_PER_B);
    const int n1 = n0 + (BN_N / BLOCKS_PER_B);
    const size_t baseP = (size_t)b * BN_N;

    for (int n = n0 + (int)threadIdx.x; n < n1; n += THREADS) {
        size_t p = baseP + n;
        StateU su;
        su.u = state[p];
        float v = 0.0f;
#pragma unroll
        for (int i = 0; i < 6; ++i) v += (float)su.s.h[i] * d[i];
        out_depth[p] = (float)su.s.h[6] - v;
    }
}

extern "C" void kernel_launch(void* const* d_in, const int* in_sizes, int n_in,
                              void* d_out, int out_size, void* d_ws, size_t ws_size,
                              hipStream_t stream) {
    const float* r     = (const float*)d_in[0];
    const float* w     = (const float*)d_in[1];
    const float* J_p   = (const float*)d_in[2];
    const float* J_d   = (const float*)d_in[3];
    const float* lmbda = (const float*)d_in[4];
    float* out = (float*)d_out;
    char* ws = (char*)d_ws;

    hipError_t err = hipErrorUnknown;
    if (ws_size >= FUSED_WS_NEEDED) {
        // Zero barrier state every call (ws is not re-poisoned between replays).
        hipMemsetAsync(ws + BAR_OFF, 0, 8192, stream);
        void* args[] = {(void*)&r, (void*)&w, (void*)&J_p, (void*)&J_d,
                        (void*)&lmbda, (void*)&ws, (void*)&out};
        err = hipLaunchCooperativeKernel(
            (const void*)k_fused3, dim3(FUSED_BLOCKS), dim3(THREADS), args, 0, stream);
    }

    if (err != hipSuccess) {
        // Fallback: proven 3-kernel path with fp16 state stash.
        float* partials = (float*)d_ws;
        uint4* state = (uint4*)(ws + STATE_OFFSET);
        dim3 grid(BLOCKS_PER_B, BN_B);
        if (ws_size >= WS_NEEDED) {
            k_reduce<true><<<grid, THREADS, 0, stream>>>(r, w, J_p, J_d, lmbda, partials, state);
            k_solve<<<dim3(BN_B), 32, 0, stream>>>(partials, lmbda, out);
            k_depth2<<<grid, THREADS, 0, stream>>>(state, out, out + 192);
        } else {
            k_reduce<false><<<grid, THREADS, 0, stream>>>(r, w, J_p, J_d, lmbda, partials, nullptr);
            k_solve<<<dim3(BN_B), 32, 0, stream>>>(partials, lmbda, out);
            k_depth2<<<grid, THREADS, 0, stream>>>(state, out, out + 192);
        }
    }
}